// Round 1
// baseline (371.606 us; speedup 1.0000x reference)
//
#include <hip/hip_runtime.h>
#include <hip/hip_bf16.h>

#define Bb 8
#define Ll 512
#define Dd 32
#define Nn 64
#define Hh 64
#define G4 256  // 4*H

__device__ __forceinline__ float fast_rcp(float x) { return __builtin_amdgcn_rcpf(x); }

__device__ __forceinline__ float fast_sigmoid(float x) {
    float xc = fminf(fmaxf(x, -30.f), 30.f);
    float e = __expf(-xc);
    return fast_rcp(1.f + e);
}

__device__ __forceinline__ float fast_tanh(float x) {
    float xc = fminf(fmaxf(x, -15.f), 15.f);
    float e = __expf(2.f * xc);          // <= e^30 ~ 1e13, no overflow
    return (e - 1.f) * fast_rcp(e + 1.f);
}

// ---------------- Kernel 1: Wx / Wxhat projections ----------------
// one thread per (b,l,n); computes both projections reusing the text row
__global__ __launch_bounds__(256) void k_proj(
    const float* __restrict__ text,
    const float* __restrict__ Wx_w, const float* __restrict__ Wx_b,
    const float* __restrict__ Wxh_w, const float* __restrict__ Wxh_b,
    float* __restrict__ Wx, float* __restrict__ Wxh) {
    int idx = blockIdx.x * 256 + threadIdx.x;   // B*L*N
    int n = idx & 63;
    int bl = idx >> 6;
    const float4* tr = (const float4*)(text + bl * Dd);
    const float4* w1 = (const float4*)(Wx_w + n * Dd);
    const float4* w2 = (const float4*)(Wxh_w + n * Dd);
    float a0 = 0.f, a1 = 0.f;
#pragma unroll
    for (int q = 0; q < 8; ++q) {
        float4 t4 = tr[q]; float4 x4 = w1[q]; float4 y4 = w2[q];
        a0 += t4.x * x4.x + t4.y * x4.y + t4.z * x4.z + t4.w * x4.w;
        a1 += t4.x * y4.x + t4.y * y4.y + t4.z * y4.z + t4.w * y4.w;
    }
    Wx[idx]  = a0 + Wx_b[n];
    Wxh[idx] = a1 + Wxh_b[n];
}

// ---------------- Kernel 2: fused attention + Xatt ----------------
// block = 256 thr (4 waves); block handles (b, 4 rows i); lane = j within a
// 64-wide j tile; never materializes A beyond one 64-wide row chunk.
__global__ __launch_bounds__(256) void k_attn(
    const float* __restrict__ text,
    const float* __restrict__ Wx, const float* __restrict__ Wxh,
    const float* __restrict__ att_w, const float* __restrict__ att_b,
    float* __restrict__ Xatt) {
    __shared__ float s_wxh[64 * 65];   // [n][j] padded
    __shared__ float s_text[32 * 65];  // [d][j] padded
    __shared__ float s_wx[4 * 64];     // Wx rows for this block's 4 i
    __shared__ float s_aw[64];
    __shared__ float s_A[4 * 64];      // per-wave A chunk

    int tid = threadIdx.x;
    int bx = blockIdx.x;           // 0..1023
    int b = bx >> 7;               // /128
    int i0 = (bx & 127) << 2;      // *4
    int w = tid >> 6, l = tid & 63;

    {   // stage Wx rows + att_w
        int wr = tid >> 6, n = tid & 63;
        s_wx[tid] = Wx[((b * Ll) + i0 + wr) * Nn + n];
        if (tid < 64) s_aw[tid] = att_w[tid];
    }
    float ab = att_b[0];
    int i = i0 + w;
    float xacc = 0.f;              // lane: d = l&31, half = l>>5
    int d = l & 31, hf = l >> 5;

    for (int jt = 0; jt < 8; ++jt) {
        __syncthreads();   // also covers initial staging
        {   // stage Wxhat tile [n][j] (transposed, coalesced global reads)
            int n = tid & 63; int j4 = tid >> 6;
#pragma unroll
            for (int r = 0; r < 16; ++r) {
                int jl = j4 + r * 4;
                s_wxh[n * 65 + jl] = Wxh[((b * Ll) + jt * 64 + jl) * Nn + n];
            }
            int dd = tid & 31; int j8 = tid >> 5;
#pragma unroll
            for (int r = 0; r < 8; ++r) {
                int jl = j8 + r * 8;
                s_text[dd * 65 + jl] = text[((b * Ll) + jt * 64 + jl) * Dd + dd];
            }
        }
        __syncthreads();
        // z = sum_n aw[n] * tanh(Wxhat[b, j, n] + Wx[b, i, n])
        float z = 0.f;
#pragma unroll
        for (int n = 0; n < 64; ++n) {
            float v = s_wxh[n * 65 + l] + s_wx[w * 64 + n];
            z += s_aw[n] * fast_tanh(v);
        }
        float Aij = fast_sigmoid(z + ab);
        s_A[w * 64 + l] = Aij;
        // Xatt partial: lanes 0..31 handle j half 0, lanes 32..63 half 1
#pragma unroll
        for (int jj = 0; jj < 32; ++jj) {
            int j = hf * 32 + jj;
            xacc += s_A[w * 64 + j] * s_text[d * 65 + j];
        }
    }
    xacc += __shfl_xor(xacc, 32);
    if (l < 32) Xatt[((b * Ll) + i) * Dd + l] = xacc;
}

// ---------------- Kernel 3: Gx = Xatt @ W_ih^T + b_ih + b_hh ----------------
__global__ __launch_bounds__(256) void k_gx(
    const float* __restrict__ Xatt,
    const float* __restrict__ W_ih, const float* __restrict__ b_ih,
    const float* __restrict__ b_hh, float* __restrict__ Gx) {
    int idx = blockIdx.x * 256 + threadIdx.x;  // B*L*256
    int g = idx & 255, bt = idx >> 8;
    const float4* xr = (const float4*)(Xatt + bt * Dd);
    const float4* wr = (const float4*)(W_ih + g * Dd);
    float a = b_ih[g] + b_hh[g];
#pragma unroll
    for (int q = 0; q < 8; ++q) {
        float4 x4 = xr[q], w4 = wr[q];
        a += x4.x * w4.x + x4.y * w4.y + x4.z * w4.z + x4.w * w4.w;
    }
    Gx[idx] = a;
}

// ---------------- Kernel 4: LSTM recurrence (one block per batch) ----------------
// 256 thr = 4 waves; lane owns gate row gid = gt*64 + u, u = 16*wave + (l%16).
// W_hh row in VGPRs; h broadcast from LDS (double-buffered, 1 barrier/step).
__global__ __launch_bounds__(256) void k_lstm(
    const float* __restrict__ Gx, const float* __restrict__ W_hh,
    const float* __restrict__ dense_w, const float* __restrict__ dense_b,
    float* __restrict__ out) {
    __shared__ __align__(16) float s_h[2][64];
    int b = blockIdx.x;
    int tid = threadIdx.x;
    int w = tid >> 6, l = tid & 63;
    int gt = l >> 4, ui = l & 15;
    int u = w * 16 + ui;
    int gid = gt * 64 + u;

    float4 wreg[16];
    const float4* wp = (const float4*)(W_hh + gid * 64);
#pragma unroll
    for (int q = 0; q < 16; ++q) wreg[q] = wp[q];

    if (tid < 64) s_h[0][tid] = 0.f;
    float c = 0.f;
    const float* gxb = Gx + b * Ll * G4;
    float gx_next = gxb[gid];
    __syncthreads();

    int buf = 0;
    for (int t = 0; t < Ll; ++t) {
        float gacc = gx_next;
        int tn = (t + 1 < Ll) ? (t + 1) : t;
        gx_next = gxb[tn * G4 + gid];     // prefetch next step's x-part
#pragma unroll
        for (int q = 0; q < 16; ++q) {
            float4 h4 = *(const float4*)&s_h[buf][q * 4];
            float4 w4 = wreg[q];
            gacc += h4.x * w4.x + h4.y * w4.y + h4.z * w4.z + h4.w * w4.w;
        }
        // gate nonlinearity: gt==2 is tanh (via 2*sigmoid(2x)-1), else sigmoid
        float xg = (gt == 2) ? 2.f * gacc : gacc;
        float s = fast_sigmoid(xg);
        float val = (gt == 2) ? 2.f * s - 1.f : s;
        // gather i,f,g,o for this unit (in-wave)
        float vi = __shfl(val, ui);
        float vf = __shfl(val, 16 + ui);
        float vg = __shfl(val, 32 + ui);
        float vo = __shfl(val, 48 + ui);
        c = vf * c + vi * vg;             // redundant across 4 gt groups, identical
        float hh = vo * fast_tanh(c);
        if (gt == 0) s_h[buf ^ 1][u] = hh;
        __syncthreads();
        buf ^= 1;
    }
    if (tid == 0) {   // dense head for this batch row
        float a0 = dense_b[0], a1 = dense_b[1];
        for (int uu = 0; uu < 64; ++uu) {
            float hv = s_h[buf][uu];
            a0 += hv * dense_w[uu];
            a1 += hv * dense_w[64 + uu];
        }
        out[b * 2 + 0] = a0;
        out[b * 2 + 1] = a1;
    }
}

extern "C" void kernel_launch(void* const* d_in, const int* in_sizes, int n_in,
                              void* d_out, int out_size, void* d_ws, size_t ws_size,
                              hipStream_t stream) {
    const float* text    = (const float*)d_in[0];
    const float* Wx_w    = (const float*)d_in[1];
    const float* Wx_b    = (const float*)d_in[2];
    const float* Wxh_w   = (const float*)d_in[3];
    const float* Wxh_b   = (const float*)d_in[4];
    const float* att_w   = (const float*)d_in[5];
    const float* att_b   = (const float*)d_in[6];
    const float* W_ih    = (const float*)d_in[7];
    const float* W_hh    = (const float*)d_in[8];
    const float* b_ih    = (const float*)d_in[9];
    const float* b_hh    = (const float*)d_in[10];
    const float* dense_w = (const float*)d_in[11];
    const float* dense_b = (const float*)d_in[12];

    float* ws   = (float*)d_ws;
    float* Wx   = ws;                 // 8*512*64   = 262144
    float* Wxh  = ws + 262144;        // 262144
    float* Xatt = ws + 524288;        // 8*512*32   = 131072
    float* Gx   = ws + 655360;        // 8*512*256  = 1048576
    float* out  = (float*)d_out;

    hipLaunchKernelGGL(k_proj, dim3((Bb * Ll * Nn) / 256), dim3(256), 0, stream,
                       text, Wx_w, Wx_b, Wxh_w, Wxh_b, Wx, Wxh);
    hipLaunchKernelGGL(k_attn, dim3(Bb * (Ll / 4)), dim3(256), 0, stream,
                       text, Wx, Wxh, att_w, att_b, Xatt);
    hipLaunchKernelGGL(k_gx, dim3((Bb * Ll * G4) / 256), dim3(256), 0, stream,
                       Xatt, W_ih, b_ih, b_hh, Gx);
    hipLaunchKernelGGL(k_lstm, dim3(Bb), dim3(256), 0, stream,
                       Gx, W_hh, dense_w, dense_b, out);
}

// Round 2
// 356.574 us; speedup vs baseline: 1.0422x; 1.0422x over previous
//
#include <hip/hip_runtime.h>
#include <hip/hip_bf16.h>

#define Bb 8
#define Ll 512
#define Dd 32
#define Nn 64
#define Hh 64
#define G4 256  // 4*H

__device__ __forceinline__ float fast_rcp(float x) { return __builtin_amdgcn_rcpf(x); }

__device__ __forceinline__ float fast_sigmoid(float x) {
    float xc = fminf(fmaxf(x, -30.f), 30.f);
    float e = __expf(-xc);
    return fast_rcp(1.f + e);
}

__device__ __forceinline__ float fast_tanh(float x) {
    float xc = fminf(fmaxf(x, -15.f), 15.f);
    float e = __expf(2.f * xc);          // <= e^30 ~ 1e13, no overflow
    return (e - 1.f) * fast_rcp(e + 1.f);
}

template<int CTRL>
__device__ __forceinline__ float quad_bcast(float v) {
    return __int_as_float(__builtin_amdgcn_mov_dpp(__float_as_int(v), CTRL, 0xf, 0xf, true));
}

// ---------------- Kernel 1: Wx / Wxhat projections ----------------
__global__ __launch_bounds__(256) void k_proj(
    const float* __restrict__ text,
    const float* __restrict__ Wx_w, const float* __restrict__ Wx_b,
    const float* __restrict__ Wxh_w, const float* __restrict__ Wxh_b,
    float* __restrict__ Wx, float* __restrict__ Wxh) {
    int idx = blockIdx.x * 256 + threadIdx.x;   // B*L*N
    int n = idx & 63;
    int bl = idx >> 6;
    const float4* tr = (const float4*)(text + bl * Dd);
    const float4* w1 = (const float4*)(Wx_w + n * Dd);
    const float4* w2 = (const float4*)(Wxh_w + n * Dd);
    float a0 = 0.f, a1 = 0.f;
#pragma unroll
    for (int q = 0; q < 8; ++q) {
        float4 t4 = tr[q]; float4 x4 = w1[q]; float4 y4 = w2[q];
        a0 += t4.x * x4.x + t4.y * x4.y + t4.z * x4.z + t4.w * x4.w;
        a1 += t4.x * y4.x + t4.y * y4.y + t4.z * y4.z + t4.w * y4.w;
    }
    Wx[idx]  = a0 + Wx_b[n];
    Wxh[idx] = a1 + Wxh_b[n];
}

// ---------------- Kernel 2: fused attention + Xatt ----------------
__global__ __launch_bounds__(256) void k_attn(
    const float* __restrict__ text,
    const float* __restrict__ Wx, const float* __restrict__ Wxh,
    const float* __restrict__ att_w, const float* __restrict__ att_b,
    float* __restrict__ Xatt) {
    __shared__ float s_wxh[64 * 65];   // [n][j] padded
    __shared__ float s_text[32 * 65];  // [d][j] padded
    __shared__ float s_wx[4 * 64];     // Wx rows for this block's 4 i
    __shared__ float s_aw[64];
    __shared__ float s_A[4 * 64];      // per-wave A chunk

    int tid = threadIdx.x;
    int bx = blockIdx.x;           // 0..1023
    int b = bx >> 7;               // /128
    int i0 = (bx & 127) << 2;      // *4
    int w = tid >> 6, l = tid & 63;

    {   // stage Wx rows + att_w
        int wr = tid >> 6, n = tid & 63;
        s_wx[tid] = Wx[((b * Ll) + i0 + wr) * Nn + n];
        if (tid < 64) s_aw[tid] = att_w[tid];
    }
    float ab = att_b[0];
    int i = i0 + w;
    float xacc = 0.f;              // lane: d = l&31, half = l>>5
    int d = l & 31, hf = l >> 5;

    for (int jt = 0; jt < 8; ++jt) {
        __syncthreads();   // also covers initial staging
        {   // stage Wxhat tile [n][j] (transposed, coalesced global reads)
            int n = tid & 63; int j4 = tid >> 6;
#pragma unroll
            for (int r = 0; r < 16; ++r) {
                int jl = j4 + r * 4;
                s_wxh[n * 65 + jl] = Wxh[((b * Ll) + jt * 64 + jl) * Nn + n];
            }
            int dd = tid & 31; int j8 = tid >> 5;
#pragma unroll
            for (int r = 0; r < 8; ++r) {
                int jl = j8 + r * 8;
                s_text[dd * 65 + jl] = text[((b * Ll) + jt * 64 + jl) * Dd + dd];
            }
        }
        __syncthreads();
        float z = 0.f;
#pragma unroll
        for (int n = 0; n < 64; ++n) {
            float v = s_wxh[n * 65 + l] + s_wx[w * 64 + n];
            z += s_aw[n] * fast_tanh(v);
        }
        float Aij = fast_sigmoid(z + ab);
        s_A[w * 64 + l] = Aij;
#pragma unroll
        for (int jj = 0; jj < 32; ++jj) {
            int j = hf * 32 + jj;
            xacc += s_A[w * 64 + j] * s_text[d * 65 + j];
        }
    }
    xacc += __shfl_xor(xacc, 32);
    if (l < 32) Xatt[((b * Ll) + i) * Dd + l] = xacc;
}

// ---------------- Kernel 3: Gx = Xatt @ W_ih^T + b_ih + b_hh ----------------
__global__ __launch_bounds__(256) void k_gx(
    const float* __restrict__ Xatt,
    const float* __restrict__ W_ih, const float* __restrict__ b_ih,
    const float* __restrict__ b_hh, float* __restrict__ Gx) {
    int idx = blockIdx.x * 256 + threadIdx.x;  // B*L*256
    int g = idx & 255, bt = idx >> 8;
    const float4* xr = (const float4*)(Xatt + bt * Dd);
    const float4* wr = (const float4*)(W_ih + g * Dd);
    float a = b_ih[g] + b_hh[g];
#pragma unroll
    for (int q = 0; q < 8; ++q) {
        float4 x4 = xr[q], w4 = wr[q];
        a += x4.x * w4.x + x4.y * w4.y + x4.z * w4.z + x4.w * w4.w;
    }
    Gx[idx] = a;
}

// ---------------- Kernel 4: LSTM recurrence (one block per batch) ----------------
// 256 thr = 4 waves. Lane l of wave w: gate g = l&3, unit u = w*16 + (l>>2).
// gid = g*64+u. i,f,g,o of one unit live in one QUAD -> gather via DPP
// quad_perm broadcasts (no LDS latency). h broadcast-read from LDS
// (uniform addresses), double-buffered, 1 barrier/step.
__global__ __launch_bounds__(256) void k_lstm(
    const float* __restrict__ Gx, const float* __restrict__ W_hh,
    const float* __restrict__ dense_w, const float* __restrict__ dense_b,
    float* __restrict__ out) {
    __shared__ __align__(16) float s_h[2][64];
    int b = blockIdx.x;
    int tid = threadIdx.x;
    int w = tid >> 6, l = tid & 63;
    int g = l & 3;
    int u = w * 16 + (l >> 2);
    int gid = g * 64 + u;

    // per-lane nonlinearity constants: gate 2 (cell input) is tanh = 2*sig(2x)-1
    float mi = (g == 2) ? 2.f : 1.f;
    float mo = (g == 2) ? 2.f : 1.f;
    float ao = (g == 2) ? -1.f : 0.f;

    float4 wreg[16];
    const float4* wp = (const float4*)(W_hh + gid * 64);
#pragma unroll
    for (int q = 0; q < 16; ++q) wreg[q] = wp[q];

    if (tid < 64) s_h[0][tid] = 0.f;
    float c = 0.f;
    const float* gxb = Gx + b * Ll * G4;
    float gx_next = gxb[gid];
    __syncthreads();

    int buf = 0;
    for (int t = 0; t < Ll; ++t) {
        const float* hb = s_h[buf];
        // load full h into regs first (uniform addr -> LDS broadcast)
        float4 hreg[16];
#pragma unroll
        for (int q = 0; q < 16; ++q) hreg[q] = *(const float4*)&hb[q * 4];

        float acc0 = gx_next, acc1 = 0.f, acc2 = 0.f, acc3 = 0.f;
        int tn = (t + 1 < Ll) ? (t + 1) : t;
        gx_next = gxb[tn * G4 + gid];     // prefetch next step's x-part
#pragma unroll
        for (int q = 0; q < 16; q += 4) {
            float4 h4, w4;
            h4 = hreg[q];     w4 = wreg[q];
            acc0 += h4.x * w4.x + h4.y * w4.y + h4.z * w4.z + h4.w * w4.w;
            h4 = hreg[q + 1]; w4 = wreg[q + 1];
            acc1 += h4.x * w4.x + h4.y * w4.y + h4.z * w4.z + h4.w * w4.w;
            h4 = hreg[q + 2]; w4 = wreg[q + 2];
            acc2 += h4.x * w4.x + h4.y * w4.y + h4.z * w4.z + h4.w * w4.w;
            h4 = hreg[q + 3]; w4 = wreg[q + 3];
            acc3 += h4.x * w4.x + h4.y * w4.y + h4.z * w4.z + h4.w * w4.w;
        }
        float gacc = (acc0 + acc1) + (acc2 + acc3);

        float s = fast_sigmoid(gacc * mi);
        float val = fmaf(s, mo, ao);      // sigmoid for i,f,o; tanh for g

        // quad gather: i,f,g,o for this unit via DPP broadcasts
        float vi = quad_bcast<0x00>(val);
        float vf = quad_bcast<0x55>(val);
        float vg = quad_bcast<0xAA>(val);
        float vo = quad_bcast<0xFF>(val);

        c = vf * c + vi * vg;             // replicated x4 per quad, identical
        float hh = vo * fast_tanh(c);
        if (g == 0) s_h[buf ^ 1][u] = hh;
        __syncthreads();
        buf ^= 1;
    }
    if (tid == 0) {   // dense head for this batch row
        float a0 = dense_b[0], a1 = dense_b[1];
        for (int uu = 0; uu < 64; ++uu) {
            float hv = s_h[buf][uu];
            a0 += hv * dense_w[uu];
            a1 += hv * dense_w[64 + uu];
        }
        out[b * 2 + 0] = a0;
        out[b * 2 + 1] = a1;
    }
}

extern "C" void kernel_launch(void* const* d_in, const int* in_sizes, int n_in,
                              void* d_out, int out_size, void* d_ws, size_t ws_size,
                              hipStream_t stream) {
    const float* text    = (const float*)d_in[0];
    const float* Wx_w    = (const float*)d_in[1];
    const float* Wx_b    = (const float*)d_in[2];
    const float* Wxh_w   = (const float*)d_in[3];
    const float* Wxh_b   = (const float*)d_in[4];
    const float* att_w   = (const float*)d_in[5];
    const float* att_b   = (const float*)d_in[6];
    const float* W_ih    = (const float*)d_in[7];
    const float* W_hh    = (const float*)d_in[8];
    const float* b_ih    = (const float*)d_in[9];
    const float* b_hh    = (const float*)d_in[10];
    const float* dense_w = (const float*)d_in[11];
    const float* dense_b = (const float*)d_in[12];

    float* ws   = (float*)d_ws;
    float* Wx   = ws;                 // 8*512*64   = 262144
    float* Wxh  = ws + 262144;        // 262144
    float* Xatt = ws + 524288;        // 8*512*32   = 131072
    float* Gx   = ws + 655360;        // 8*512*256  = 1048576
    float* out  = (float*)d_out;

    hipLaunchKernelGGL(k_proj, dim3((Bb * Ll * Nn) / 256), dim3(256), 0, stream,
                       text, Wx_w, Wx_b, Wxh_w, Wxh_b, Wx, Wxh);
    hipLaunchKernelGGL(k_attn, dim3(Bb * (Ll / 4)), dim3(256), 0, stream,
                       text, Wx, Wxh, att_w, att_b, Xatt);
    hipLaunchKernelGGL(k_gx, dim3((Bb * Ll * G4) / 256), dim3(256), 0, stream,
                       Xatt, W_ih, b_ih, b_hh, Gx);
    hipLaunchKernelGGL(k_lstm, dim3(Bb), dim3(256), 0, stream,
                       Gx, W_hh, dense_w, dense_b, out);
}

// Round 3
// 323.521 us; speedup vs baseline: 1.1486x; 1.1022x over previous
//
#include <hip/hip_runtime.h>
#include <hip/hip_bf16.h>

#define Bb 8
#define Ll 512
#define Dd 32
#define Nn 64
#define Hh 64
#define G4 256  // 4*H

__device__ __forceinline__ float fast_rcp(float x) { return __builtin_amdgcn_rcpf(x); }

__device__ __forceinline__ float fast_sigmoid(float x) {
    float xc = fminf(fmaxf(x, -30.f), 30.f);
    float e = __expf(-xc);
    return fast_rcp(1.f + e);
}

__device__ __forceinline__ float fast_tanh(float x) {
    float xc = fminf(fmaxf(x, -15.f), 15.f);
    float e = __expf(2.f * xc);          // <= e^30 ~ 1e13, no overflow
    return (e - 1.f) * fast_rcp(e + 1.f);
}

template<int CTRL>
__device__ __forceinline__ float quad_dpp(float v) {
    return __int_as_float(__builtin_amdgcn_mov_dpp(__float_as_int(v), CTRL, 0xf, 0xf, true));
}

// sum across a quad (lanes 4k..4k+3); xor1 = quad_perm[1,0,3,2] = 0xB1,
// xor2 = quad_perm[2,3,0,1] = 0x4E. Result identical on all 4 lanes.
__device__ __forceinline__ float quad_sum(float v) {
    v += quad_dpp<0xB1>(v);
    v += quad_dpp<0x4E>(v);
    return v;
}

// ---------------- Kernel 1: Wx / Wxhat projections ----------------
__global__ __launch_bounds__(256) void k_proj(
    const float* __restrict__ text,
    const float* __restrict__ Wx_w, const float* __restrict__ Wx_b,
    const float* __restrict__ Wxh_w, const float* __restrict__ Wxh_b,
    float* __restrict__ Wx, float* __restrict__ Wxh) {
    int idx = blockIdx.x * 256 + threadIdx.x;   // B*L*N
    int n = idx & 63;
    int bl = idx >> 6;
    const float4* tr = (const float4*)(text + bl * Dd);
    const float4* w1 = (const float4*)(Wx_w + n * Dd);
    const float4* w2 = (const float4*)(Wxh_w + n * Dd);
    float a0 = 0.f, a1 = 0.f;
#pragma unroll
    for (int q = 0; q < 8; ++q) {
        float4 t4 = tr[q]; float4 x4 = w1[q]; float4 y4 = w2[q];
        a0 += t4.x * x4.x + t4.y * x4.y + t4.z * x4.z + t4.w * x4.w;
        a1 += t4.x * y4.x + t4.y * y4.y + t4.z * y4.z + t4.w * y4.w;
    }
    Wx[idx]  = a0 + Wx_b[n];
    Wxh[idx] = a1 + Wxh_b[n];
}

// ---------------- Kernel 2: fused attention + Xatt ----------------
__global__ __launch_bounds__(256) void k_attn(
    const float* __restrict__ text,
    const float* __restrict__ Wx, const float* __restrict__ Wxh,
    const float* __restrict__ att_w, const float* __restrict__ att_b,
    float* __restrict__ Xatt) {
    __shared__ float s_wxh[64 * 65];   // [n][j] padded
    __shared__ float s_text[32 * 65];  // [d][j] padded
    __shared__ float s_wx[4 * 64];     // Wx rows for this block's 4 i
    __shared__ float s_aw[64];
    __shared__ float s_A[4 * 64];      // per-wave A chunk

    int tid = threadIdx.x;
    int bx = blockIdx.x;           // 0..1023
    int b = bx >> 7;               // /128
    int i0 = (bx & 127) << 2;      // *4
    int w = tid >> 6, l = tid & 63;

    {   // stage Wx rows + att_w
        int wr = tid >> 6, n = tid & 63;
        s_wx[tid] = Wx[((b * Ll) + i0 + wr) * Nn + n];
        if (tid < 64) s_aw[tid] = att_w[tid];
    }
    float ab = att_b[0];
    int i = i0 + w;
    float xacc = 0.f;              // lane: d = l&31, half = l>>5
    int d = l & 31, hf = l >> 5;

    for (int jt = 0; jt < 8; ++jt) {
        __syncthreads();   // also covers initial staging
        {   // stage Wxhat tile [n][j] (transposed, coalesced global reads)
            int n = tid & 63; int j4 = tid >> 6;
#pragma unroll
            for (int r = 0; r < 16; ++r) {
                int jl = j4 + r * 4;
                s_wxh[n * 65 + jl] = Wxh[((b * Ll) + jt * 64 + jl) * Nn + n];
            }
            int dd = tid & 31; int j8 = tid >> 5;
#pragma unroll
            for (int r = 0; r < 8; ++r) {
                int jl = j8 + r * 8;
                s_text[dd * 65 + jl] = text[((b * Ll) + jt * 64 + jl) * Dd + dd];
            }
        }
        __syncthreads();
        float z = 0.f;
#pragma unroll
        for (int n = 0; n < 64; ++n) {
            float v = s_wxh[n * 65 + l] + s_wx[w * 64 + n];
            z += s_aw[n] * fast_tanh(v);
        }
        float Aij = fast_sigmoid(z + ab);
        s_A[w * 64 + l] = Aij;
#pragma unroll
        for (int jj = 0; jj < 32; ++jj) {
            int j = hf * 32 + jj;
            xacc += s_A[w * 64 + j] * s_text[d * 65 + j];
        }
    }
    xacc += __shfl_xor(xacc, 32);
    if (l < 32) Xatt[((b * Ll) + i) * Dd + l] = xacc;
}

// ---------------- Kernel 3: Gx = Xatt @ W_ih^T + b_ih + b_hh ----------------
__global__ __launch_bounds__(256) void k_gx(
    const float* __restrict__ Xatt,
    const float* __restrict__ W_ih, const float* __restrict__ b_ih,
    const float* __restrict__ b_hh, float* __restrict__ Gx) {
    int idx = blockIdx.x * 256 + threadIdx.x;  // B*L*256
    int g = idx & 255, bt = idx >> 8;
    const float4* xr = (const float4*)(Xatt + bt * Dd);
    const float4* wr = (const float4*)(W_ih + g * Dd);
    float a = b_ih[g] + b_hh[g];
#pragma unroll
    for (int q = 0; q < 8; ++q) {
        float4 x4 = xr[q], w4 = wr[q];
        a += x4.x * w4.x + x4.y * w4.y + x4.z * w4.z + x4.w * w4.w;
    }
    Gx[idx] = a;
}

// ---------------- Kernel 4: LSTM recurrence (one block per batch) ----------------
// 256 thr = 4 waves. Lane l of wave w: part p = l&3, unit u = w*16 + (l>>2).
// Each lane computes PARTIAL dots (16 of 64 h-elements) for ALL 4 gates of
// its unit -> 4x less LDS read traffic (4 x b128/lane vs 16). Quad DPP
// butterfly reduces parts; every lane then holds all 4 gate totals and
// updates c,h redundantly (bit-identical within quad). 1 barrier/step,
// double-buffered h, distance-2 Gx prefetch (cold HBM ~900cy ~ 2 steps).
__global__ __launch_bounds__(256) void k_lstm(
    const float* __restrict__ Gx, const float* __restrict__ W_hh,
    const float* __restrict__ dense_w, const float* __restrict__ dense_b,
    float* __restrict__ out) {
    __shared__ __align__(16) float s_h[2][64];
    int b = blockIdx.x;
    int tid = threadIdx.x;
    int w = tid >> 6, l = tid & 63;
    int p = l & 3;                 // h-slice [16p, 16p+16)
    int u = w * 16 + (l >> 2);     // unit

    // wreg[g][q] = W_hh[g*64+u][p*16 + 4q .. +4)
    float4 wreg[4][4];
#pragma unroll
    for (int g = 0; g < 4; ++g) {
        const float4* wp = (const float4*)(W_hh + (g * 64 + u) * 64 + p * 16);
#pragma unroll
        for (int q = 0; q < 4; ++q) wreg[g][q] = wp[q];
    }

    if (tid < 64) s_h[0][tid] = 0.f;
    float c = 0.f;
    const float* gxb = Gx + b * Ll * G4;
    int gidx = p * 64 + u;         // this lane's gx element (gate p, unit u)
    float gx_cur = gxb[gidx];             // t = 0
    float gx_n1  = gxb[G4 + gidx];        // t = 1
    __syncthreads();

    int buf = 0;
    for (int t = 0; t < Ll; ++t) {
        // prefetch t+2 (in flight ~2 steps)
        int t2 = (t + 2 < Ll) ? (t + 2) : (Ll - 1);
        float gx_n2 = gxb[t2 * G4 + gidx];

        const float4* hb = (const float4*)(s_h[buf] + p * 16);
        float4 h0 = hb[0], h1 = hb[1], h2 = hb[2], h3 = hb[3];

        // partial dots for the 4 gates over this lane's 16-element slice;
        // gx for gate p injected into acc_p exactly once per quad
        float a0 = (p == 0) ? gx_cur : 0.f;
        float a1 = (p == 1) ? gx_cur : 0.f;
        float a2 = (p == 2) ? gx_cur : 0.f;
        float a3 = (p == 3) ? gx_cur : 0.f;
        {
            float4 w4;
            w4 = wreg[0][0]; a0 += h0.x*w4.x + h0.y*w4.y + h0.z*w4.z + h0.w*w4.w;
            w4 = wreg[0][1]; a0 += h1.x*w4.x + h1.y*w4.y + h1.z*w4.z + h1.w*w4.w;
            w4 = wreg[0][2]; a0 += h2.x*w4.x + h2.y*w4.y + h2.z*w4.z + h2.w*w4.w;
            w4 = wreg[0][3]; a0 += h3.x*w4.x + h3.y*w4.y + h3.z*w4.z + h3.w*w4.w;
            w4 = wreg[1][0]; a1 += h0.x*w4.x + h0.y*w4.y + h0.z*w4.z + h0.w*w4.w;
            w4 = wreg[1][1]; a1 += h1.x*w4.x + h1.y*w4.y + h1.z*w4.z + h1.w*w4.w;
            w4 = wreg[1][2]; a1 += h2.x*w4.x + h2.y*w4.y + h2.z*w4.z + h2.w*w4.w;
            w4 = wreg[1][3]; a1 += h3.x*w4.x + h3.y*w4.y + h3.z*w4.z + h3.w*w4.w;
            w4 = wreg[2][0]; a2 += h0.x*w4.x + h0.y*w4.y + h0.z*w4.z + h0.w*w4.w;
            w4 = wreg[2][1]; a2 += h1.x*w4.x + h1.y*w4.y + h1.z*w4.z + h1.w*w4.w;
            w4 = wreg[2][2]; a2 += h2.x*w4.x + h2.y*w4.y + h2.z*w4.z + h2.w*w4.w;
            w4 = wreg[2][3]; a2 += h3.x*w4.x + h3.y*w4.y + h3.z*w4.z + h3.w*w4.w;
            w4 = wreg[3][0]; a3 += h0.x*w4.x + h0.y*w4.y + h0.z*w4.z + h0.w*w4.w;
            w4 = wreg[3][1]; a3 += h1.x*w4.x + h1.y*w4.y + h1.z*w4.z + h1.w*w4.w;
            w4 = wreg[3][2]; a3 += h2.x*w4.x + h2.y*w4.y + h2.z*w4.z + h2.w*w4.w;
            w4 = wreg[3][3]; a3 += h3.x*w4.x + h3.y*w4.y + h3.z*w4.z + h3.w*w4.w;
        }
        // quad reduce: every lane gets all four gate totals (bit-identical)
        float ti = quad_sum(a0);
        float tf = quad_sum(a1);
        float tg = quad_sum(a2);
        float to = quad_sum(a3);

        float gi = fast_sigmoid(ti);
        float gf = fast_sigmoid(tf);
        float gg = fast_tanh(tg);
        float go = fast_sigmoid(to);
        c = gf * c + gi * gg;
        float hh = go * fast_tanh(c);
        if (p == 0) s_h[buf ^ 1][u] = hh;
        __syncthreads();
        buf ^= 1;
        gx_cur = gx_n1;
        gx_n1 = gx_n2;
    }
    if (tid == 0) {   // dense head for this batch row
        float a0 = dense_b[0], a1 = dense_b[1];
        for (int uu = 0; uu < 64; ++uu) {
            float hv = s_h[buf][uu];
            a0 += hv * dense_w[uu];
            a1 += hv * dense_w[64 + uu];
        }
        out[b * 2 + 0] = a0;
        out[b * 2 + 1] = a1;
    }
}

extern "C" void kernel_launch(void* const* d_in, const int* in_sizes, int n_in,
                              void* d_out, int out_size, void* d_ws, size_t ws_size,
                              hipStream_t stream) {
    const float* text    = (const float*)d_in[0];
    const float* Wx_w    = (const float*)d_in[1];
    const float* Wx_b    = (const float*)d_in[2];
    const float* Wxh_w   = (const float*)d_in[3];
    const float* Wxh_b   = (const float*)d_in[4];
    const float* att_w   = (const float*)d_in[5];
    const float* att_b   = (const float*)d_in[6];
    const float* W_ih    = (const float*)d_in[7];
    const float* W_hh    = (const float*)d_in[8];
    const float* b_ih    = (const float*)d_in[9];
    const float* b_hh    = (const float*)d_in[10];
    const float* dense_w = (const float*)d_in[11];
    const float* dense_b = (const float*)d_in[12];

    float* ws   = (float*)d_ws;
    float* Wx   = ws;                 // 8*512*64   = 262144
    float* Wxh  = ws + 262144;        // 262144
    float* Xatt = ws + 524288;        // 8*512*32   = 131072
    float* Gx   = ws + 655360;        // 8*512*256  = 1048576
    float* out  = (float*)d_out;

    hipLaunchKernelGGL(k_proj, dim3((Bb * Ll * Nn) / 256), dim3(256), 0, stream,
                       text, Wx_w, Wx_b, Wxh_w, Wxh_b, Wx, Wxh);
    hipLaunchKernelGGL(k_attn, dim3(Bb * (Ll / 4)), dim3(256), 0, stream,
                       text, Wx, Wxh, att_w, att_b, Xatt);
    hipLaunchKernelGGL(k_gx, dim3((Bb * Ll * G4) / 256), dim3(256), 0, stream,
                       Xatt, W_ih, b_ih, b_hh, Gx);
    hipLaunchKernelGGL(k_lstm, dim3(Bb), dim3(256), 0, stream,
                       Gx, W_hh, dense_w, dense_b, out);
}

// Round 5
// 219.043 us; speedup vs baseline: 1.6965x; 1.4770x over previous
//
#include <hip/hip_runtime.h>
#include <hip/hip_bf16.h>

#define Bb 8
#define Ll 512
#define Dd 32
#define Nn 64
#define Hh 64
#define G4 256  // 4*H

#define L2E  1.4426950408889634f   // log2(e)
#define L2E2 2.8853900817779268f   // 2*log2(e)

typedef _Float16 h2_t __attribute__((ext_vector_type(2)));

__device__ __forceinline__ float fast_rcp(float x) { return __builtin_amdgcn_rcpf(x); }
// v_exp_f32 computes 2^x directly
__device__ __forceinline__ float fast_exp2(float x) { return __builtin_amdgcn_exp2f(x); }

// sigmoid(x) = 1/(1+e^-x) = rcp(1+exp2(-x*log2e)); saturates gracefully, no clamps
__device__ __forceinline__ float sig2(float x) {
    return fast_rcp(1.f + fast_exp2(-L2E * x));
}
// tanh(x) = 2*sigmoid(2x)-1
__device__ __forceinline__ float tanh2(float x) {
    return fmaf(2.f, fast_rcp(1.f + fast_exp2(-L2E2 * x)), -1.f);
}

__device__ __forceinline__ float fdot2(h2_t a, h2_t b, float c) {
#if __has_builtin(__builtin_amdgcn_fdot2)
    return __builtin_amdgcn_fdot2(a, b, c, false);
#else
    return c + (float)a[0] * (float)b[0] + (float)a[1] * (float)b[1];
#endif
}

template<int CTRL>
__device__ __forceinline__ float quad_dpp(float v) {
    return __int_as_float(__builtin_amdgcn_mov_dpp(__float_as_int(v), CTRL, 0xf, 0xf, true));
}
__device__ __forceinline__ float quad_sum(float v) {
    v += quad_dpp<0xB1>(v);   // quad_perm [1,0,3,2]
    v += quad_dpp<0x4E>(v);   // quad_perm [2,3,0,1]
    return v;
}

// ---------------- Kernel 1: exp-space projections ----------------
// Ex = exp2(2*log2e*(text@Wx^T+b)), Eh = exp2(2*log2e*(text@Wxhat^T+b))
// so that e^{2(wx_i+wxh_j)} = Ex_i * Eh_j in the attention inner loop.
__global__ __launch_bounds__(256) void k_proj(
    const float* __restrict__ text,
    const float* __restrict__ Wx_w, const float* __restrict__ Wx_b,
    const float* __restrict__ Wxh_w, const float* __restrict__ Wxh_b,
    float* __restrict__ Ex, float* __restrict__ Eh) {
    int idx = blockIdx.x * 256 + threadIdx.x;   // B*L*N
    int n = idx & 63;
    int bl = idx >> 6;
    const float4* tr = (const float4*)(text + bl * Dd);
    const float4* w1 = (const float4*)(Wx_w + n * Dd);
    const float4* w2 = (const float4*)(Wxh_w + n * Dd);
    float a0 = 0.f, a1 = 0.f;
#pragma unroll
    for (int q = 0; q < 8; ++q) {
        float4 t4 = tr[q]; float4 x4 = w1[q]; float4 y4 = w2[q];
        a0 += t4.x * x4.x + t4.y * x4.y + t4.z * x4.z + t4.w * x4.w;
        a1 += t4.x * y4.x + t4.y * y4.y + t4.z * y4.z + t4.w * y4.w;
    }
    Ex[idx] = fast_exp2(L2E2 * (a0 + Wx_b[n]));
    Eh[idx] = fast_exp2(L2E2 * (a1 + Wxh_b[n]));
}

// ---------------- Kernel 2: fused attention + Xatt (factored exp) ----------------
// tanh(wxh+wx) = 1 - 2*rcp(E*F+1) with E=e^{2wxh}, F=e^{2wx} precomputed.
// z = sum_n aw_n tanh(.) = awsum - 2*sum_n aw_n*rcp(E_n*F_n+1).
__global__ __launch_bounds__(256) void k_attn(
    const float* __restrict__ text,
    const float* __restrict__ Ex, const float* __restrict__ Eh,
    const float* __restrict__ att_w, const float* __restrict__ att_b,
    float* __restrict__ Xatt) {
    __shared__ float s_eh[64 * 65];    // Eh tile [n][j] padded
    __shared__ float s_text[32 * 65];  // text tile [d][j] padded
    __shared__ float2 s_fa[4 * 64];    // (F, aw) per (wave-row, n)
    __shared__ float s_A[4 * 64];      // per-wave A chunk

    int tid = threadIdx.x;
    int bx = blockIdx.x;           // 0..1023
    int b = bx >> 7;               // /128
    int i0 = (bx & 127) << 2;      // *4
    int w = tid >> 6, l = tid & 63;
    int i = i0 + w;

    // stage (F, aw) pairs for this block's 4 i-rows
    s_fa[w * 64 + l] = make_float2(Ex[((b * Ll) + i) * Nn + l], att_w[l]);
    float ab = att_b[0];
    __syncthreads();

    float awsum = 0.f;
#pragma unroll
    for (int n = 0; n < 64; ++n) awsum += s_fa[w * 64 + n].y;
    float zc = awsum + ab;

    float xacc = 0.f;              // lane: d = l&31, half = l>>5
    int d = l & 31, hf = l >> 5;

    for (int jt = 0; jt < 8; ++jt) {
        __syncthreads();
        {   // stage Eh tile [n][j] + text tile [d][j]
            int n = tid & 63; int j4 = tid >> 6;
#pragma unroll
            for (int r = 0; r < 16; ++r) {
                int jl = j4 + r * 4;
                s_eh[n * 65 + jl] = Eh[((b * Ll) + jt * 64 + jl) * Nn + n];
            }
            int dd = tid & 31; int j8 = tid >> 5;
#pragma unroll
            for (int r = 0; r < 8; ++r) {
                int jl = j8 + r * 8;
                s_text[dd * 65 + jl] = text[((b * Ll) + jt * 64 + jl) * Dd + dd];
            }
        }
        __syncthreads();
        float S = 0.f;
#pragma unroll
        for (int n = 0; n < 64; ++n) {
            float E = s_eh[n * 65 + l];
            float2 fa = s_fa[w * 64 + n];
            float r = fast_rcp(fmaf(E, fa.x, 1.f));
            S = fmaf(fa.y, r, S);
        }
        // A = sigmoid(awsum - 2S + ab)
        float A = fast_rcp(1.f + fast_exp2(-L2E * (zc - 2.f * S)));
        s_A[w * 64 + l] = A;
#pragma unroll
        for (int jj = 0; jj < 32; ++jj) {
            int j = hf * 32 + jj;
            xacc += s_A[w * 64 + j] * s_text[d * 65 + j];
        }
    }
    xacc += __shfl_xor(xacc, 32);
    if (l < 32) Xatt[((b * Ll) + i) * Dd + l] = xacc;
}

// ---------------- Kernel 3: Gx = Xatt @ W_ih^T + b_ih + b_hh ----------------
__global__ __launch_bounds__(256) void k_gx(
    const float* __restrict__ Xatt,
    const float* __restrict__ W_ih, const float* __restrict__ b_ih,
    const float* __restrict__ b_hh, float* __restrict__ Gx) {
    int idx = blockIdx.x * 256 + threadIdx.x;  // B*L*256
    int g = idx & 255, bt = idx >> 8;
    const float4* xr = (const float4*)(Xatt + bt * Dd);
    const float4* wr = (const float4*)(W_ih + g * Dd);
    float a = b_ih[g] + b_hh[g];
#pragma unroll
    for (int q = 0; q < 8; ++q) {
        float4 x4 = xr[q], w4 = wr[q];
        a += x4.x * w4.x + x4.y * w4.y + x4.z * w4.z + x4.w * w4.w;
    }
    Gx[idx] = a;
}

// ---------------- Kernel 4: LSTM recurrence (one block per batch) ----------------
// 4 waves. Lane: part p = l&3 (16-elem h slice), unit u = w*16 + (l>>2).
// h kept in LDS as f16; W_hh as half2 in VGPRs; partial dots via v_dot2_f32_f16
// (32 instrs/lane/step), quad DPP reduce, lean exp2/rcp nonlinearities.
// c stays fp32 per-lane. 1 barrier/step, double-buffered h, dist-2 Gx prefetch.
__global__ __launch_bounds__(256) void k_lstm(
    const float* __restrict__ Gx, const float* __restrict__ W_hh,
    const float* __restrict__ dense_w, const float* __restrict__ dense_b,
    float* __restrict__ out) {
    __shared__ __align__(16) _Float16 s_h[2][64];
    int b = blockIdx.x;
    int tid = threadIdx.x;
    int w = tid >> 6, l = tid & 63;
    int p = l & 3;                 // h-slice [16p, 16p+16)
    int u = w * 16 + (l >> 2);     // unit

    // wreg[g][q] = half2 of W_hh[g*64+u][p*16 + 2q .. +2)
    h2_t wreg[4][8];
#pragma unroll
    for (int g = 0; g < 4; ++g) {
        const float4* wp = (const float4*)(W_hh + (g * 64 + u) * 64 + p * 16);
#pragma unroll
        for (int q = 0; q < 4; ++q) {
            float4 v = wp[q];
            wreg[g][2 * q]     = h2_t{(_Float16)v.x, (_Float16)v.y};
            wreg[g][2 * q + 1] = h2_t{(_Float16)v.z, (_Float16)v.w};
        }
    }

    if (tid < 64) s_h[0][tid] = (_Float16)0.f;
    float c = 0.f;
    const float* gxb = Gx + b * Ll * G4;
    int gidx = p * 64 + u;         // this lane's gx element (gate p, unit u)
    float gx_cur = gxb[gidx];             // t = 0
    float gx_n1  = gxb[G4 + gidx];        // t = 1
    __syncthreads();

    int buf = 0;
    for (int t = 0; t < Ll; ++t) {
        int t2 = (t + 2 < Ll) ? (t + 2) : (Ll - 1);
        float gx_n2 = gxb[t2 * G4 + gidx];   // dist-2 prefetch

        // read this lane's 16-half slice of h as 2 x b128
        union { float4 f; h2_t h[4]; } u0, u1;
        u0.f = *(const float4*)(&s_h[buf][p * 16]);
        u1.f = *(const float4*)(&s_h[buf][p * 16 + 8]);

        float a0 = (p == 0) ? gx_cur : 0.f;
        float a1 = (p == 1) ? gx_cur : 0.f;
        float a2 = (p == 2) ? gx_cur : 0.f;
        float a3 = (p == 3) ? gx_cur : 0.f;
#pragma unroll
        for (int q = 0; q < 4; ++q) {
            a0 = fdot2(u0.h[q], wreg[0][q], a0);
            a1 = fdot2(u0.h[q], wreg[1][q], a1);
            a2 = fdot2(u0.h[q], wreg[2][q], a2);
            a3 = fdot2(u0.h[q], wreg[3][q], a3);
        }
#pragma unroll
        for (int q = 0; q < 4; ++q) {
            a0 = fdot2(u1.h[q], wreg[0][q + 4], a0);
            a1 = fdot2(u1.h[q], wreg[1][q + 4], a1);
            a2 = fdot2(u1.h[q], wreg[2][q + 4], a2);
            a3 = fdot2(u1.h[q], wreg[3][q + 4], a3);
        }
        // quad reduce: every lane gets all four gate totals
        float ti = quad_sum(a0);
        float tf = quad_sum(a1);
        float tg = quad_sum(a2);
        float to = quad_sum(a3);

        float gi = sig2(ti);
        float gf = sig2(tf);
        float gg = tanh2(tg);
        float go = sig2(to);
        c = fmaf(gf, c, gi * gg);
        float hh = go * tanh2(c);
        if (p == 0) s_h[buf ^ 1][u] = (_Float16)hh;
        __syncthreads();
        buf ^= 1;
        gx_cur = gx_n1;
        gx_n1 = gx_n2;
    }
    if (tid == 0) {   // dense head for this batch row
        float a0 = dense_b[0], a1 = dense_b[1];
        for (int uu = 0; uu < 64; ++uu) {
            float hv = (float)s_h[buf][uu];
            a0 += hv * dense_w[uu];
            a1 += hv * dense_w[64 + uu];
        }
        out[b * 2 + 0] = a0;
        out[b * 2 + 1] = a1;
    }
}

extern "C" void kernel_launch(void* const* d_in, const int* in_sizes, int n_in,
                              void* d_out, int out_size, void* d_ws, size_t ws_size,
                              hipStream_t stream) {
    const float* text    = (const float*)d_in[0];
    const float* Wx_w    = (const float*)d_in[1];
    const float* Wx_b    = (const float*)d_in[2];
    const float* Wxh_w   = (const float*)d_in[3];
    const float* Wxh_b   = (const float*)d_in[4];
    const float* att_w   = (const float*)d_in[5];
    const float* att_b   = (const float*)d_in[6];
    const float* W_ih    = (const float*)d_in[7];
    const float* W_hh    = (const float*)d_in[8];
    const float* b_ih    = (const float*)d_in[9];
    const float* b_hh    = (const float*)d_in[10];
    const float* dense_w = (const float*)d_in[11];
    const float* dense_b = (const float*)d_in[12];

    float* ws   = (float*)d_ws;
    float* Ex   = ws;                 // 8*512*64   = 262144
    float* Eh   = ws + 262144;        // 262144
    float* Xatt = ws + 524288;        // 8*512*32   = 131072
    float* Gx   = ws + 655360;        // 8*512*256  = 1048576
    float* out  = (float*)d_out;

    hipLaunchKernelGGL(k_proj, dim3((Bb * Ll * Nn) / 256), dim3(256), 0, stream,
                       text, Wx_w, Wx_b, Wxh_w, Wxh_b, Ex, Eh);
    hipLaunchKernelGGL(k_attn, dim3(Bb * (Ll / 4)), dim3(256), 0, stream,
                       text, Ex, Eh, att_w, att_b, Xatt);
    hipLaunchKernelGGL(k_gx, dim3((Bb * Ll * G4) / 256), dim3(256), 0, stream,
                       Xatt, W_ih, b_ih, b_hh, Gx);
    hipLaunchKernelGGL(k_lstm, dim3(Bb), dim3(256), 0, stream,
                       Gx, W_hh, dense_w, dense_b, out);
}

// Round 6
// 203.169 us; speedup vs baseline: 1.8291x; 1.0781x over previous
//
#include <hip/hip_runtime.h>
#include <hip/hip_bf16.h>

#define Bb 8
#define Ll 512
#define Dd 32
#define Nn 64
#define Hh 64
#define G4 256  // 4*H

#define L2E  1.4426950408889634f   // log2(e)
#define L2E2 2.8853900817779268f   // 2*log2(e)

typedef _Float16 h2_t __attribute__((ext_vector_type(2)));

__device__ __forceinline__ float fast_rcp(float x) { return __builtin_amdgcn_rcpf(x); }
// v_exp_f32 computes 2^x directly
__device__ __forceinline__ float fast_exp2(float x) { return __builtin_amdgcn_exp2f(x); }

// sigmoid(x) = rcp(1+exp2(-x*log2e)); saturates gracefully, no clamps
__device__ __forceinline__ float sig2(float x) {
    return fast_rcp(1.f + fast_exp2(-L2E * x));
}
// tanh(x) = 2*sigmoid(2x)-1
__device__ __forceinline__ float tanh2(float x) {
    return fmaf(2.f, fast_rcp(1.f + fast_exp2(-L2E2 * x)), -1.f);
}

__device__ __forceinline__ float fdot2(h2_t a, h2_t b, float c) {
#if __has_builtin(__builtin_amdgcn_fdot2)
    return __builtin_amdgcn_fdot2(a, b, c, false);
#else
    return c + (float)a[0] * (float)b[0] + (float)a[1] * (float)b[1];
#endif
}

template<int CTRL>
__device__ __forceinline__ float quad_dpp(float v) {
    return __int_as_float(__builtin_amdgcn_mov_dpp(__float_as_int(v), CTRL, 0xf, 0xf, true));
}
__device__ __forceinline__ float quad_sum(float v) {
    v += quad_dpp<0xB1>(v);   // quad_perm [1,0,3,2]
    v += quad_dpp<0x4E>(v);   // quad_perm [2,3,0,1]
    return v;
}

// ---------------- Kernel 1: exp-space projections ----------------
// Ex = exp2(2*log2e*(text@Wx^T+b)), Eh = exp2(2*log2e*(text@Wxhat^T+b))
// so that e^{2(wx_i+wxh_j)} = Ex_i * Eh_j in the attention inner loop.
__global__ __launch_bounds__(256) void k_proj(
    const float* __restrict__ text,
    const float* __restrict__ Wx_w, const float* __restrict__ Wx_b,
    const float* __restrict__ Wxh_w, const float* __restrict__ Wxh_b,
    float* __restrict__ Ex, float* __restrict__ Eh) {
    int idx = blockIdx.x * 256 + threadIdx.x;   // B*L*N
    int n = idx & 63;
    int bl = idx >> 6;
    const float4* tr = (const float4*)(text + bl * Dd);
    const float4* w1 = (const float4*)(Wx_w + n * Dd);
    const float4* w2 = (const float4*)(Wxh_w + n * Dd);
    float a0 = 0.f, a1 = 0.f;
#pragma unroll
    for (int q = 0; q < 8; ++q) {
        float4 t4 = tr[q]; float4 x4 = w1[q]; float4 y4 = w2[q];
        a0 += t4.x * x4.x + t4.y * x4.y + t4.z * x4.z + t4.w * x4.w;
        a1 += t4.x * y4.x + t4.y * y4.y + t4.z * y4.z + t4.w * y4.w;
    }
    Ex[idx] = fast_exp2(L2E2 * (a0 + Wx_b[n]));
    Eh[idx] = fast_exp2(L2E2 * (a1 + Wxh_b[n]));
}

// ---------------- Kernel 2: fused attention + Xatt + Gx ----------------
// tanh(wxh+wx) = 1 - 2*rcp(E*F+1) with E=e^{2wxh}, F=e^{2wx} precomputed.
// z = sum_n aw_n tanh(.) = awsum - 2*sum_n aw_n*rcp(E_n*F_n+1).
// Epilogue computes Gx = Xatt@W_ih^T + b_ih + b_hh for this block's 4 rows
// (kills the separate k_gx kernel + the Xatt global round-trip).
__global__ __launch_bounds__(256) void k_attn(
    const float* __restrict__ text,
    const float* __restrict__ Ex, const float* __restrict__ Eh,
    const float* __restrict__ att_w, const float* __restrict__ att_b,
    const float* __restrict__ W_ih, const float* __restrict__ b_ih,
    const float* __restrict__ b_hh, float* __restrict__ Gx) {
    __shared__ float s_eh[64 * 65];    // Eh tile [n][j] padded
    __shared__ float s_text[32 * 65];  // text tile [d][j] padded
    __shared__ float2 s_fa[4 * 64];    // (F, aw) per (wave-row, n)
    __shared__ float s_A[4 * 64];      // per-wave A chunk
    __shared__ __align__(16) float s_xatt[4][32];  // finished Xatt rows

    int tid = threadIdx.x;
    int bx = blockIdx.x;           // 0..1023
    int b = bx >> 7;               // /128
    int i0 = (bx & 127) << 2;      // *4
    int w = tid >> 6, l = tid & 63;
    int i = i0 + w;

    // stage (F, aw) pairs for this block's 4 i-rows
    s_fa[w * 64 + l] = make_float2(Ex[((b * Ll) + i) * Nn + l], att_w[l]);
    float ab = att_b[0];
    __syncthreads();

    float awsum = 0.f;
#pragma unroll
    for (int n = 0; n < 64; ++n) awsum += s_fa[w * 64 + n].y;
    float zc = awsum + ab;

    float xacc = 0.f;              // lane: d = l&31, half = l>>5
    int d = l & 31, hf = l >> 5;

    for (int jt = 0; jt < 8; ++jt) {
        __syncthreads();
        {   // stage Eh tile [n][j] + text tile [d][j]
            int n = tid & 63; int j4 = tid >> 6;
#pragma unroll
            for (int r = 0; r < 16; ++r) {
                int jl = j4 + r * 4;
                s_eh[n * 65 + jl] = Eh[((b * Ll) + jt * 64 + jl) * Nn + n];
            }
            int dd = tid & 31; int j8 = tid >> 5;
#pragma unroll
            for (int r = 0; r < 8; ++r) {
                int jl = j8 + r * 8;
                s_text[dd * 65 + jl] = text[((b * Ll) + jt * 64 + jl) * Dd + dd];
            }
        }
        __syncthreads();
        float S = 0.f;
#pragma unroll
        for (int n = 0; n < 64; ++n) {
            float E = s_eh[n * 65 + l];
            float2 fa = s_fa[w * 64 + n];
            float r = fast_rcp(fmaf(E, fa.x, 1.f));
            S = fmaf(fa.y, r, S);
        }
        // A = sigmoid(awsum - 2S + ab)
        float A = fast_rcp(1.f + fast_exp2(-L2E * (zc - 2.f * S)));
        s_A[w * 64 + l] = A;
#pragma unroll
        for (int jj = 0; jj < 32; ++jj) {
            int j = hf * 32 + jj;
            xacc += s_A[w * 64 + j] * s_text[d * 65 + j];
        }
    }
    xacc += __shfl_xor(xacc, 32);
    if (l < 32) s_xatt[w][l] = xacc;   // lanes 0..31 hold d = l
    __syncthreads();

    // ---- fused Gx epilogue: thread tid = gate g, rows i0..i0+3 ----
    {
        int g = tid;
        const float4* wr = (const float4*)(W_ih + g * Dd);
        float4 wv[8];
#pragma unroll
        for (int q = 0; q < 8; ++q) wv[q] = wr[q];
        float bias = b_ih[g] + b_hh[g];
#pragma unroll
        for (int r = 0; r < 4; ++r) {
            const float4* xr = (const float4*)s_xatt[r];  // LDS broadcast reads
            float acc = bias;
#pragma unroll
            for (int q = 0; q < 8; ++q) {
                float4 x4 = xr[q]; float4 w4 = wv[q];
                acc += x4.x * w4.x + x4.y * w4.y + x4.z * w4.z + x4.w * w4.w;
            }
            Gx[((b * Ll) + i0 + r) * G4 + g] = acc;
        }
    }
}

// ---------------- Kernel 3: LSTM recurrence (one block per batch) ----------------
// 4 waves. Lane: part p = l&3 (16-elem h slice), unit u = w*16 + (l>>2).
// h in LDS as f16; W_hh as half2 in VGPRs; partials via v_dot2_f32_f16.
// Quad reduce -> lane p selects gate p's total, applies ONE activation
// (per-lane consts: gate2=tanh, else sigmoid), DPP-broadcasts the four
// activated gates back. c fp32/lane. 1 barrier/step, dist-2 Gx prefetch.
__global__ __launch_bounds__(256) void k_lstm(
    const float* __restrict__ Gx, const float* __restrict__ W_hh,
    const float* __restrict__ dense_w, const float* __restrict__ dense_b,
    float* __restrict__ out) {
    __shared__ __align__(16) _Float16 s_h[2][64];
    int b = blockIdx.x;
    int tid = threadIdx.x;
    int w = tid >> 6, l = tid & 63;
    int p = l & 3;                 // h-slice [16p, 16p+16)
    int u = w * 16 + (l >> 2);     // unit

    // per-lane activation constants: gate 2 (cell input) is tanh = 2*sig(2x)-1
    float pm = (p == 2) ? -L2E2 : -L2E;
    float mo = (p == 2) ? 2.f : 1.f;
    float ao = (p == 2) ? -1.f : 0.f;

    // wreg[g][q] = half2 of W_hh[g*64+u][p*16 + 2q .. +2)
    h2_t wreg[4][8];
#pragma unroll
    for (int g = 0; g < 4; ++g) {
        const float4* wp = (const float4*)(W_hh + (g * 64 + u) * 64 + p * 16);
#pragma unroll
        for (int q = 0; q < 4; ++q) {
            float4 v = wp[q];
            wreg[g][2 * q]     = h2_t{(_Float16)v.x, (_Float16)v.y};
            wreg[g][2 * q + 1] = h2_t{(_Float16)v.z, (_Float16)v.w};
        }
    }

    if (tid < 64) s_h[0][tid] = (_Float16)0.f;
    float c = 0.f;
    const float* gxb = Gx + b * Ll * G4;
    int gidx = p * 64 + u;         // this lane's gx element (gate p, unit u)
    float gx_cur = gxb[gidx];             // t = 0
    float gx_n1  = gxb[G4 + gidx];        // t = 1
    __syncthreads();

    int buf = 0;
    for (int t = 0; t < Ll; ++t) {
        int t2 = (t + 2 < Ll) ? (t + 2) : (Ll - 1);
        float gx_n2 = gxb[t2 * G4 + gidx];   // dist-2 prefetch

        // read this lane's 16-half slice of h as 2 x b128
        union { float4 f; h2_t h[4]; } u0, u1;
        u0.f = *(const float4*)(&s_h[buf][p * 16]);
        u1.f = *(const float4*)(&s_h[buf][p * 16 + 8]);

        float a0 = (p == 0) ? gx_cur : 0.f;
        float a1 = (p == 1) ? gx_cur : 0.f;
        float a2 = (p == 2) ? gx_cur : 0.f;
        float a3 = (p == 3) ? gx_cur : 0.f;
#pragma unroll
        for (int q = 0; q < 4; ++q) {
            a0 = fdot2(u0.h[q], wreg[0][q], a0);
            a1 = fdot2(u0.h[q], wreg[1][q], a1);
            a2 = fdot2(u0.h[q], wreg[2][q], a2);
            a3 = fdot2(u0.h[q], wreg[3][q], a3);
        }
#pragma unroll
        for (int q = 0; q < 4; ++q) {
            a0 = fdot2(u1.h[q], wreg[0][q + 4], a0);
            a1 = fdot2(u1.h[q], wreg[1][q + 4], a1);
            a2 = fdot2(u1.h[q], wreg[2][q + 4], a2);
            a3 = fdot2(u1.h[q], wreg[3][q + 4], a3);
        }
        // full quad totals for all four gates (every lane)
        float ti = quad_sum(a0);
        float tf = quad_sum(a1);
        float tg = quad_sum(a2);
        float to = quad_sum(a3);
        // lane p takes gate p's total, applies its single activation
        float tot = (p & 2) ? ((p & 1) ? to : tg) : ((p & 1) ? tf : ti);
        float val = fmaf(mo, fast_rcp(1.f + fast_exp2(pm * tot)), ao);
        // redistribute activated gates within the quad
        float vi = quad_dpp<0x00>(val);
        float vf = quad_dpp<0x55>(val);
        float vg = quad_dpp<0xAA>(val);
        float vo = quad_dpp<0xFF>(val);

        c = fmaf(vf, c, vi * vg);
        float hh = vo * tanh2(c);
        if (p == 0) s_h[buf ^ 1][u] = (_Float16)hh;
        __syncthreads();
        buf ^= 1;
        gx_cur = gx_n1;
        gx_n1 = gx_n2;
    }
    if (tid == 0) {   // dense head for this batch row
        float a0 = dense_b[0], a1 = dense_b[1];
        for (int uu = 0; uu < 64; ++uu) {
            float hv = (float)s_h[buf][uu];
            a0 += hv * dense_w[uu];
            a1 += hv * dense_w[64 + uu];
        }
        out[b * 2 + 0] = a0;
        out[b * 2 + 1] = a1;
    }
}

extern "C" void kernel_launch(void* const* d_in, const int* in_sizes, int n_in,
                              void* d_out, int out_size, void* d_ws, size_t ws_size,
                              hipStream_t stream) {
    const float* text    = (const float*)d_in[0];
    const float* Wx_w    = (const float*)d_in[1];
    const float* Wx_b    = (const float*)d_in[2];
    const float* Wxh_w   = (const float*)d_in[3];
    const float* Wxh_b   = (const float*)d_in[4];
    const float* att_w   = (const float*)d_in[5];
    const float* att_b   = (const float*)d_in[6];
    const float* W_ih    = (const float*)d_in[7];
    const float* W_hh    = (const float*)d_in[8];
    const float* b_ih    = (const float*)d_in[9];
    const float* b_hh    = (const float*)d_in[10];
    const float* dense_w = (const float*)d_in[11];
    const float* dense_b = (const float*)d_in[12];

    float* ws   = (float*)d_ws;
    float* Ex   = ws;                 // 8*512*64   = 262144
    float* Eh   = ws + 262144;        // 262144
    float* Gx   = ws + 655360;        // 8*512*256  = 1048576
    float* out  = (float*)d_out;

    hipLaunchKernelGGL(k_proj, dim3((Bb * Ll * Nn) / 256), dim3(256), 0, stream,
                       text, Wx_w, Wx_b, Wxh_w, Wxh_b, Ex, Eh);
    hipLaunchKernelGGL(k_attn, dim3(Bb * (Ll / 4)), dim3(256), 0, stream,
                       text, Ex, Eh, att_w, att_b, W_ih, b_ih, b_hh, Gx);
    hipLaunchKernelGGL(k_lstm, dim3(Bb), dim3(256), 0, stream,
                       Gx, W_hh, dense_w, dense_b, out);
}